// Round 20
// baseline (307.972 us; speedup 1.0000x reference)
//
#include <hip/hip_runtime.h>
#include <hip/hip_bf16.h>

#define B_  32
#define T_  2048
#define DH_ 1024
#define DS_ 1024
#define A_  512
#define M_  (B_ * T_)   // 65536
#define NCH 16          // t-chunks per batch (128 rows each)

typedef __attribute__((ext_vector_type(8))) short bf16x8;
typedef __attribute__((ext_vector_type(4))) float f32x4;

__device__ __forceinline__ unsigned short f2bf(float f) {
    union { float f; unsigned u; } v; v.f = f;
    unsigned r = 0x7FFFu + ((v.u >> 16) & 1u);
    return (unsigned short)((v.u + r) >> 16);
}
__device__ __forceinline__ float fast_tanh(float x) {
    float cx = fminf(fmaxf(x, -9.f), 9.f);
    float e2 = __expf(2.f * cx);
    return (e2 - 1.f) / (e2 + 1.f);
}
__device__ __forceinline__ unsigned pack_bf2(float lo, float hi) {
    union { float f; unsigned u; } a, b;
    a.f = lo; b.f = hi;
    return __builtin_amdgcn_perm(b.u + 0x8000u, a.u + 0x8000u, 0x07060302u);
}

// ---- U_t[a][k] = bf16(U_a[k][a]) -----------------------------------------
__global__ void prep_ut(const float* __restrict__ U, unsigned short* __restrict__ Ut) {
    int o = blockIdx.x * 256 + threadIdx.x;
    int a = o >> 10, k = o & (DH_ - 1);
    Ut[o] = f2bf(U[k * A_ + a]);
}

// ---- Ws[b][a] = s[b,:] . W_a[:,a]  (k-split 4-way + LDS reduce) ----------
__global__ void ws_gemv2(const float* __restrict__ s, const float* __restrict__ W,
                         float* __restrict__ Ws) {
    __shared__ float red[4][64];
    const int blk = blockIdx.x;
    const int b = blk >> 3, a0 = (blk & 7) * 64;
    const int tid = threadIdx.x;
    const int a = a0 + (tid & 63), kq = tid >> 6;
    const float* sp = s + b * DS_ + kq * 256;
    const float* wp = W + (size_t)(kq * 256) * A_ + a;
    float acc = 0.f;
#pragma unroll 8
    for (int k = 0; k < 256; ++k) acc += sp[k] * wp[(size_t)k * A_];
    red[kq][tid & 63] = acc;
    __syncthreads();
    if (tid < 64)
        Ws[b * A_ + a0 + tid] = red[0][tid] + red[1][tid] + red[2][tid] + red[3][tid];
}

// ---- fused: per-(batch, 128-row chunk). ZERO-BARRIER, ZERO-LDS K-loop
// (R18 design, spill fixed): launch_bounds(512,1) gives the 256-VGPR/wave
// budget; bq single-buffered. Register tally ~230 -> no spill. Per step:
// packA (waits A(t) via counted vmcnt), issue A(t+1), 32 MFMA (compiler
// waits B(t) at vmcnt(8) while A(t+1) flies), issue B(t+1). B(t) L2
// latency hides under step t-1's MFMA; waves slip freely (no barriers).
// Epilogue/softmax/ctx = R15 champion verbatim.
__global__ void __launch_bounds__(512, 1)
fused_direct2(const float* __restrict__ h,
              const unsigned short* __restrict__ Ut,
              const float* __restrict__ Ws, const float* __restrict__ va,
              float* __restrict__ pm, float* __restrict__ pl,
              float* __restrict__ pc) {
    __shared__ float smem[896];                 // epilogue only (3.6 KB)

    const int tid = threadIdx.x;
    const int tm = blockIdx.x;                  // 512 = b*16 + chunk
    const int rowBase = tm * 128;

    const int lane = tid & 63;
    const int wid = tid >> 6;                   // 8 waves: 2(M) x 4(N)
    const int wm = wid >> 2, wn = wid & 3;      // wave: 64 m-rows x 128 a-cols
    const int lr = lane & 15, kg = lane >> 4;

    f32x4 acc[4][8];
#pragma unroll
    for (int i = 0; i < 4; ++i)
#pragma unroll
        for (int j = 0; j < 8; ++j) acc[i][j] = (f32x4){0.f, 0.f, 0.f, 0.f};

    // per-lane fragment base pointers (both patterns full-line coalesced)
    const float* abase = h + (size_t)(rowBase + wm * 64 + lr) * DH_ + kg * 8;
    const unsigned short* bbase = Ut + (size_t)(wn * 128 + lr) * DH_ + kg * 8;

    auto loadAf32 = [&](float4* at, int t) {    // 8 global dwordx4 (f32)
#pragma unroll
        for (int mi = 0; mi < 4; ++mi) {
            const float* p = abase + (size_t)mi * 16 * DH_ + t * 32;
            at[2 * mi]     = *(const float4*)p;
            at[2 * mi + 1] = *(const float4*)(p + 4);
        }
    };
    auto packA = [&](const float4* at, bf16x8* af) {
#pragma unroll
        for (int mi = 0; mi < 4; ++mi) {
            union { bf16x8 v; uint4 u; } q;
            q.u.x = pack_bf2(at[2 * mi].x, at[2 * mi].y);
            q.u.y = pack_bf2(at[2 * mi].z, at[2 * mi].w);
            q.u.z = pack_bf2(at[2 * mi + 1].x, at[2 * mi + 1].y);
            q.u.w = pack_bf2(at[2 * mi + 1].z, at[2 * mi + 1].w);
            af[mi] = q.v;
        }
    };
    auto loadB = [&](bf16x8* bq, int t) {       // 8 global dwordx4 (bf16)
        const unsigned short* bp = bbase + t * 32;
#pragma unroll
        for (int nf = 0; nf < 8; ++nf)
            bq[nf] = *(const bf16x8*)(bp + (size_t)nf * 16 * DH_);
    };

    float4 at[8];
    bf16x8 af[4], bq[8];
    const int NT = DH_ / 32;                    // 32 K-steps

    // prologue: A(0) and B(0) in flight
    loadAf32(at, 0);
    loadB(bq, 0);

#pragma unroll 1
    for (int t = 0; t < NT; ++t) {
        const bool more = (t < NT - 1);
        packA(at, af);                          // waits on A(t) loads only
        if (more) loadAf32(at, t + 1);          // issue next A (flies thru MFMA)
        __builtin_amdgcn_s_setprio(1);
#pragma unroll
        for (int mi = 0; mi < 4; ++mi)
#pragma unroll
            for (int nf = 0; nf < 8; ++nf)
                acc[mi][nf] = __builtin_amdgcn_mfma_f32_16x16x32_bf16(
                    af[mi], bq[nf], acc[mi][nf], 0, 0, 0);
        __builtin_amdgcn_s_setprio(0);
        if (more) loadB(bq, t + 1);             // WAR-safe: issued after MFMA reads
    }

    // ---- phase 2a: e_r = sum_a tanh(acc + Ws) * v  -> er_s[128] ----------
    float* er_s  = smem;                        // 128
    float* red_s = smem + 128;                  // 128
    float* w_s   = smem + 256;                  // 128
    float* pf    = smem + 384;                  // 512

    const int bIdx = rowBase >> 11;
    const float* WsRow = Ws + bIdx * A_;
    float wsv[8], vav[8];
#pragma unroll
    for (int nf = 0; nf < 8; ++nf) {
        int a = wn * 128 + nf * 16 + lr;
        wsv[nf] = WsRow[a];
        vav[nf] = va[a];
    }
#pragma unroll
    for (int mi = 0; mi < 4; ++mi) {
#pragma unroll
        for (int j = 0; j < 4; ++j) {
            float ssum = 0.f;
#pragma unroll
            for (int nf = 0; nf < 8; ++nf) {
                float x = acc[mi][nf][j] + wsv[nf];
                ssum += fast_tanh(x) * vav[nf];
            }
            ssum += __shfl_xor(ssum, 1);
            ssum += __shfl_xor(ssum, 2);
            ssum += __shfl_xor(ssum, 4);
            ssum += __shfl_xor(ssum, 8);
            if (lr == 0) {
                int r = wm * 64 + mi * 16 + kg * 4 + j;
                pf[r * 4 + wn] = ssum;
            }
        }
    }
    __syncthreads();
    if (tid < 128) {
        float v = pf[tid * 4] + pf[tid * 4 + 1] + pf[tid * 4 + 2] + pf[tid * 4 + 3];
        er_s[tid] = v;
        red_s[tid] = v;
    }
    __syncthreads();
    if (tid < 64) red_s[tid] = fmaxf(red_s[tid], red_s[tid + 64]);
    __syncthreads();
    if (tid < 32) red_s[tid] = fmaxf(red_s[tid], red_s[tid + 32]);
    __syncthreads();
    if (tid < 16) red_s[tid] = fmaxf(red_s[tid], red_s[tid + 16]);
    __syncthreads();
    if (tid < 8) red_s[tid] = fmaxf(red_s[tid], red_s[tid + 8]);
    __syncthreads();
    if (tid < 4) red_s[tid] = fmaxf(red_s[tid], red_s[tid + 4]);
    __syncthreads();
    if (tid < 2) red_s[tid] = fmaxf(red_s[tid], red_s[tid + 2]);
    __syncthreads();
    if (tid == 0) red_s[0] = fmaxf(red_s[0], red_s[1]);
    __syncthreads();
    const float mloc = red_s[0];
    __syncthreads();
    if (tid < 128) {
        float w = __expf(er_s[tid] - mloc);
        w_s[tid] = w;
        red_s[tid] = w;
    }
    __syncthreads();
    if (tid < 64) red_s[tid] += red_s[tid + 64];
    __syncthreads();
    if (tid < 32) red_s[tid] += red_s[tid + 32];
    __syncthreads();
    if (tid < 16) red_s[tid] += red_s[tid + 16];
    __syncthreads();
    if (tid < 8) red_s[tid] += red_s[tid + 8];
    __syncthreads();
    if (tid < 4) red_s[tid] += red_s[tid + 4];
    __syncthreads();
    if (tid < 2) red_s[tid] += red_s[tid + 2];
    __syncthreads();
    if (tid == 0) {
        pm[tm] = mloc;
        pl[tm] = red_s[0] + red_s[1];
    }

    // ---- phase 3: partial context c_i[d] = sum_t w_t h[t][d] (L2-warm) ---
    float c0 = 0.f, c1 = 0.f;
    const float* hp = h + (size_t)rowBase * DH_ + tid;
#pragma unroll 4
    for (int t = 0; t < 128; ++t) {
        float w = w_s[t];
        c0 += w * hp[(size_t)t * DH_];
        c1 += w * hp[(size_t)t * DH_ + 512];
    }
    float* pcp = pc + (size_t)tm * DH_;
    pcp[tid] = c0;
    pcp[tid + 512] = c1;
}

// ---- combine: c[b][d] = sum_i exp(m_i-M) c_i[d] / sum_i exp(m_i-M) l_i ---
__global__ void combine(const float* __restrict__ pm, const float* __restrict__ pl,
                        const float* __restrict__ pc, float* __restrict__ c) {
    const int b = blockIdx.x;
    const int tid = threadIdx.x;
    float M = -1e30f;
#pragma unroll
    for (int i = 0; i < NCH; ++i) M = fmaxf(M, pm[b * NCH + i]);
    float L = 0.f;
    float sc[NCH];
#pragma unroll
    for (int i = 0; i < NCH; ++i) {
        sc[i] = __expf(pm[b * NCH + i] - M);
        L += sc[i] * pl[b * NCH + i];
    }
    float a0 = 0.f, a1 = 0.f;
#pragma unroll
    for (int i = 0; i < NCH; ++i) {
        const float* pcp = pc + (size_t)(b * NCH + i) * DH_;
        a0 += sc[i] * pcp[tid];
        a1 += sc[i] * pcp[tid + 512];
    }
    const float inv = 1.f / L;
    c[(size_t)b * DH_ + tid] = a0 * inv;
    c[(size_t)b * DH_ + tid + 512] = a1 * inv;
}

extern "C" void kernel_launch(void* const* d_in, const int* in_sizes, int n_in,
                              void* d_out, int out_size, void* d_ws, size_t ws_size,
                              hipStream_t stream) {
    const float* s   = (const float*)d_in[0];
    const float* h   = (const float*)d_in[1];
    const float* W_a = (const float*)d_in[2];
    const float* U_a = (const float*)d_in[3];
    const float* v_a = (const float*)d_in[4];
    float* c = (float*)d_out;

    // ws: Ws [16384 f32] | Ut [524288 bf16] | pm [512] | pl [512] | pc [512*1024]
    float* Ws = (float*)d_ws;
    unsigned short* Ut = (unsigned short*)(Ws + B_ * A_);
    float* pm = (float*)(Ut + (size_t)A_ * DH_);
    float* pl = pm + B_ * NCH;
    float* pc = pl + B_ * NCH;

    prep_ut<<<(A_ * DH_) / 256, 256, 0, stream>>>(U_a, Ut);
    ws_gemv2<<<B_ * 8, 256, 0, stream>>>(s, W_a, Ws);
    fused_direct2<<<B_ * NCH, 512, 0, stream>>>(h, Ut, Ws, v_a, pm, pl, pc);
    combine<<<B_, 512, 0, stream>>>(pm, pl, pc, c);
}

// Round 21
// 180.938 us; speedup vs baseline: 1.7021x; 1.7021x over previous
//
#include <hip/hip_runtime.h>
#include <hip/hip_bf16.h>

#define B_  32
#define T_  2048
#define DH_ 1024
#define DS_ 1024
#define A_  512
#define M_  (B_ * T_)   // 65536
#define NCH 16          // t-chunks per batch (128 rows each)

typedef __attribute__((ext_vector_type(8))) short bf16x8;
typedef __attribute__((ext_vector_type(4))) float f32x4;

__device__ __forceinline__ unsigned short f2bf(float f) {
    union { float f; unsigned u; } v; v.f = f;
    unsigned r = 0x7FFFu + ((v.u >> 16) & 1u);
    return (unsigned short)((v.u + r) >> 16);
}
__device__ __forceinline__ float fast_tanh(float x) {
    float cx = fminf(fmaxf(x, -9.f), 9.f);
    float e2 = __expf(2.f * cx);
    return (e2 - 1.f) / (e2 + 1.f);
}
__device__ __forceinline__ unsigned pack_bf2(float lo, float hi) {
    union { float f; unsigned u; } a, b;
    a.f = lo; b.f = hi;
    return __builtin_amdgcn_perm(b.u + 0x8000u, a.u + 0x8000u, 0x07060302u);
}

// ---- U_t[a][k] = bf16(U_a[k][a]) -----------------------------------------
__global__ void prep_ut(const float* __restrict__ U, unsigned short* __restrict__ Ut) {
    int o = blockIdx.x * 256 + threadIdx.x;
    int a = o >> 10, k = o & (DH_ - 1);
    Ut[o] = f2bf(U[k * A_ + a]);
}

// ---- Ws[b][a] = s[b,:] . W_a[:,a]  (k-split 4-way + LDS reduce) ----------
__global__ void ws_gemv2(const float* __restrict__ s, const float* __restrict__ W,
                         float* __restrict__ Ws) {
    __shared__ float red[4][64];
    const int blk = blockIdx.x;
    const int b = blk >> 3, a0 = (blk & 7) * 64;
    const int tid = threadIdx.x;
    const int a = a0 + (tid & 63), kq = tid >> 6;
    const float* sp = s + b * DS_ + kq * 256;
    const float* wp = W + (size_t)(kq * 256) * A_ + a;
    float acc = 0.f;
#pragma unroll 8
    for (int k = 0; k < 256; ++k) acc += sp[k] * wp[(size_t)k * A_];
    red[kq][tid & 63] = acc;
    __syncthreads();
    if (tid < 64)
        Ws[b * A_ + a0 + tid] = red[0][tid] + red[1][tid] + red[2][tid] + red[3][tid];
}

// ---- fused: per-(batch, 128-row chunk): e-GEMM (R14-proven loop) ->
// local softmax (m, l, w) -> partial context from L2-warm h.
// Outputs pm[chunk], pl[chunk], pc[chunk][1024].  (R15 champion, verbatim.)
__global__ void __launch_bounds__(512, 2)
fused_chunk(const float* __restrict__ h,
            const unsigned short* __restrict__ Ut,
            const float* __restrict__ Ws, const float* __restrict__ va,
            float* __restrict__ pm, float* __restrict__ pl,
            float* __restrict__ pc) {
    __shared__ unsigned short As[2][128][32];   // 16 KB
    __shared__ unsigned short Bs[2][512][32];   // 64 KB

    const int tid = threadIdx.x;
    const int tm = blockIdx.x;                  // 512 = b*16 + chunk
    const int rowBase = tm * 128;

    const int lane = tid & 63;
    const int wid = tid >> 6;                   // 8 waves: 2(M) x 4(N)
    const int wm = wid >> 2, wn = wid & 3;      // wave tile 64(m) x 128(n)
    const int lr = lane & 15, kg = lane >> 4;
    const int gsw16 = (kg ^ ((lr >> 1) & 3)) * 8;

    const int ar = tid >> 2;                    // A-staging row
    const int alg = tid & 3;                    // logical granule (8 f32)

    f32x4 acc[4][8];
#pragma unroll
    for (int i = 0; i < 4; ++i)
#pragma unroll
        for (int j = 0; j < 8; ++j) acc[i][j] = (f32x4){0.f, 0.f, 0.f, 0.f};

    auto loadA = [&](float4* areg, int t) {
        const float* hp = h + (size_t)(rowBase + ar) * DH_ + t * 32 + alg * 8;
        areg[0] = *(const float4*)(hp);
        areg[1] = *(const float4*)(hp + 4);
    };
    auto stageB = [&](int buf, int t) {
        const int k0 = t * 32;
#pragma unroll
        for (int j = 0; j < 4; ++j) {
            int byt = j * 8192 + tid * 16;
            int r = byt >> 6;                   // row 0..511
            int g = ((byt >> 4) & 3) ^ ((r >> 1) & 3);
            const unsigned short* gb = Ut + (size_t)r * DH_ + k0 + g * 8;
            __builtin_amdgcn_global_load_lds(
                (const __attribute__((address_space(1))) unsigned int*)gb,
                (__attribute__((address_space(3))) unsigned int*)(&Bs[buf][0][0] + (byt >> 1)),
                16, 0, 0);
        }
    };
    auto packwriteA = [&](const float4* areg, int buf) {
        uint4 u;
        u.x = pack_bf2(areg[0].x, areg[0].y);
        u.y = pack_bf2(areg[0].z, areg[0].w);
        u.z = pack_bf2(areg[1].x, areg[1].y);
        u.w = pack_bf2(areg[1].z, areg[1].w);
        int p = alg ^ ((ar >> 1) & 3);
        *(uint4*)((char*)&As[buf][0][0] + ar * 64 + p * 16) = u;
    };

    float4 areg[2];
    const int NT = DH_ / 32;

    loadA(areg, 0);
    __builtin_amdgcn_sched_barrier(0);
    stageB(0, 0);
    __builtin_amdgcn_sched_barrier(0);
    packwriteA(areg, 0);
    asm volatile("s_waitcnt vmcnt(0) lgkmcnt(0)" ::: "memory");
    __builtin_amdgcn_s_barrier();
    __builtin_amdgcn_sched_barrier(0);

#pragma unroll 1
    for (int t = 0; t < NT; ++t) {
        const int buf = t & 1;
        const bool more = (t < NT - 1);
        if (more) {
            loadA(areg, t + 1);
            __builtin_amdgcn_sched_barrier(0);
            stageB(buf ^ 1, t + 1);
            __builtin_amdgcn_sched_barrier(0);
        }

        const unsigned short* Ab = &As[buf][0][0];
        const unsigned short* Bb = &Bs[buf][0][0];
        bf16x8 af[4], bq[8];
#pragma unroll
        for (int nf = 0; nf < 8; ++nf)
            bq[nf] = *(const bf16x8*)(Bb + (wn * 128 + nf * 16 + lr) * 32 + gsw16);
#pragma unroll
        for (int mi = 0; mi < 4; ++mi)
            af[mi] = *(const bf16x8*)(Ab + (wm * 64 + mi * 16 + lr) * 32 + gsw16);
        asm volatile("s_waitcnt lgkmcnt(0)" ::: "memory");
        __builtin_amdgcn_sched_barrier(0);

        __builtin_amdgcn_s_setprio(1);
#pragma unroll
        for (int mi = 0; mi < 4; ++mi)
#pragma unroll
            for (int nf = 0; nf < 8; ++nf)
                acc[mi][nf] = __builtin_amdgcn_mfma_f32_16x16x32_bf16(
                    af[mi], bq[nf], acc[mi][nf], 0, 0, 0);
        __builtin_amdgcn_s_setprio(0);
        __builtin_amdgcn_sched_barrier(0);

        if (more) {
            packwriteA(areg, buf ^ 1);
            asm volatile("s_waitcnt vmcnt(0) lgkmcnt(0)" ::: "memory");
            __builtin_amdgcn_s_barrier();
            __builtin_amdgcn_sched_barrier(0);
        }
    }
    __syncthreads();                            // As free for reuse

    // ---- phase 2a: e_r = sum_a tanh(acc + Ws) * v  -> er_s[128] ----------
    float* er_s  = (float*)&As[0][0][0];
    float* red_s = er_s + 128;
    float* w_s   = er_s + 256;
    float* pf    = er_s + 384;

    const int bIdx = rowBase >> 11;
    const float* WsRow = Ws + bIdx * A_;
    float wsv[8], vav[8];
#pragma unroll
    for (int nf = 0; nf < 8; ++nf) {
        int a = wn * 128 + nf * 16 + lr;
        wsv[nf] = WsRow[a];
        vav[nf] = va[a];
    }
#pragma unroll
    for (int mi = 0; mi < 4; ++mi) {
#pragma unroll
        for (int j = 0; j < 4; ++j) {
            float ssum = 0.f;
#pragma unroll
            for (int nf = 0; nf < 8; ++nf) {
                float x = acc[mi][nf][j] + wsv[nf];
                ssum += fast_tanh(x) * vav[nf];
            }
            ssum += __shfl_xor(ssum, 1);
            ssum += __shfl_xor(ssum, 2);
            ssum += __shfl_xor(ssum, 4);
            ssum += __shfl_xor(ssum, 8);
            if (lr == 0) {
                int r = wm * 64 + mi * 16 + kg * 4 + j;
                pf[r * 4 + wn] = ssum;
            }
        }
    }
    __syncthreads();
    if (tid < 128) {
        float v = pf[tid * 4] + pf[tid * 4 + 1] + pf[tid * 4 + 2] + pf[tid * 4 + 3];
        er_s[tid] = v;
        red_s[tid] = v;
    }
    __syncthreads();
    if (tid < 64) red_s[tid] = fmaxf(red_s[tid], red_s[tid + 64]);
    __syncthreads();
    if (tid < 32) red_s[tid] = fmaxf(red_s[tid], red_s[tid + 32]);
    __syncthreads();
    if (tid < 16) red_s[tid] = fmaxf(red_s[tid], red_s[tid + 16]);
    __syncthreads();
    if (tid < 8) red_s[tid] = fmaxf(red_s[tid], red_s[tid + 8]);
    __syncthreads();
    if (tid < 4) red_s[tid] = fmaxf(red_s[tid], red_s[tid + 4]);
    __syncthreads();
    if (tid < 2) red_s[tid] = fmaxf(red_s[tid], red_s[tid + 2]);
    __syncthreads();
    if (tid == 0) red_s[0] = fmaxf(red_s[0], red_s[1]);
    __syncthreads();
    const float mloc = red_s[0];
    __syncthreads();
    if (tid < 128) {
        float w = __expf(er_s[tid] - mloc);
        w_s[tid] = w;
        red_s[tid] = w;
    }
    __syncthreads();
    if (tid < 64) red_s[tid] += red_s[tid + 64];
    __syncthreads();
    if (tid < 32) red_s[tid] += red_s[tid + 32];
    __syncthreads();
    if (tid < 16) red_s[tid] += red_s[tid + 16];
    __syncthreads();
    if (tid < 8) red_s[tid] += red_s[tid + 8];
    __syncthreads();
    if (tid < 4) red_s[tid] += red_s[tid + 4];
    __syncthreads();
    if (tid < 2) red_s[tid] += red_s[tid + 2];
    __syncthreads();
    if (tid == 0) {
        pm[tm] = mloc;
        pl[tm] = red_s[0] + red_s[1];
    }

    // ---- phase 3: partial context c_i[d] = sum_t w_t h[t][d] (L2-warm) ---
    float c0 = 0.f, c1 = 0.f;
    const float* hp = h + (size_t)rowBase * DH_ + tid;
#pragma unroll 4
    for (int t = 0; t < 128; ++t) {
        float w = w_s[t];
        c0 += w * hp[(size_t)t * DH_];
        c1 += w * hp[(size_t)t * DH_ + 512];
    }
    float* pcp = pc + (size_t)tm * DH_;
    pcp[tid] = c0;
    pcp[tid + 512] = c1;
}

// ---- combine: c[b][d] = sum_i exp(m_i-M) c_i[d] / sum_i exp(m_i-M) l_i ---
__global__ void combine(const float* __restrict__ pm, const float* __restrict__ pl,
                        const float* __restrict__ pc, float* __restrict__ c) {
    const int b = blockIdx.x;
    const int tid = threadIdx.x;
    float M = -1e30f;
#pragma unroll
    for (int i = 0; i < NCH; ++i) M = fmaxf(M, pm[b * NCH + i]);
    float L = 0.f;
    float sc[NCH];
#pragma unroll
    for (int i = 0; i < NCH; ++i) {
        sc[i] = __expf(pm[b * NCH + i] - M);
        L += sc[i] * pl[b * NCH + i];
    }
    float a0 = 0.f, a1 = 0.f;
#pragma unroll
    for (int i = 0; i < NCH; ++i) {
        const float* pcp = pc + (size_t)(b * NCH + i) * DH_;
        a0 += sc[i] * pcp[tid];
        a1 += sc[i] * pcp[tid + 512];
    }
    const float inv = 1.f / L;
    c[(size_t)b * DH_ + tid] = a0 * inv;
    c[(size_t)b * DH_ + tid + 512] = a1 * inv;
}

extern "C" void kernel_launch(void* const* d_in, const int* in_sizes, int n_in,
                              void* d_out, int out_size, void* d_ws, size_t ws_size,
                              hipStream_t stream) {
    const float* s   = (const float*)d_in[0];
    const float* h   = (const float*)d_in[1];
    const float* W_a = (const float*)d_in[2];
    const float* U_a = (const float*)d_in[3];
    const float* v_a = (const float*)d_in[4];
    float* c = (float*)d_out;

    // ws: Ws [16384 f32] | Ut [524288 bf16] | pm [512] | pl [512] | pc [512*1024]
    float* Ws = (float*)d_ws;
    unsigned short* Ut = (unsigned short*)(Ws + B_ * A_);
    float* pm = (float*)(Ut + (size_t)A_ * DH_);
    float* pl = pm + B_ * NCH;
    float* pc = pl + B_ * NCH;

    prep_ut<<<(A_ * DH_) / 256, 256, 0, stream>>>(U_a, Ut);
    ws_gemv2<<<B_ * 8, 256, 0, stream>>>(s, W_a, Ws);
    fused_chunk<<<B_ * NCH, 512, 0, stream>>>(h, Ut, Ws, v_a, pm, pl, pc);
    combine<<<B_, 512, 0, stream>>>(pm, pl, pc, c);
}